// Round 1
// 300.916 us; speedup vs baseline: 1.1770x; 1.1770x over previous
//
#include <hip/hip_runtime.h>
#include <math.h>

#define PRIME_Y 2654435761u

struct LevelParams { float scale; unsigned res; unsigned size; unsigned offset; };
struct EncParams { LevelParams lv[16]; };

typedef __attribute__((ext_vector_type(8))) short short8;
typedef __attribute__((ext_vector_type(4))) float f32x4;

struct alignas(8) F2 { float x, y; };

// fp32 pair -> packed bf16 (RNE), low = a, high = b.
// gfx950 v_cvt_pk_bf16_f32: 1 VALU op vs ~8 for the manual bit-RNE.
__device__ inline unsigned bf2pack(float a, float b) {
  unsigned r;
  asm("v_cvt_pk_bf16_f32 %0, %1, %2" : "=v"(r) : "v"(a), "v"(b));
  return r;
}
__device__ inline F2 bf2unpack(unsigned u) {
  F2 r;
  r.x = __uint_as_float(u << 16);
  r.y = __uint_as_float(u & 0xFFFF0000u);
  return r;
}

// Fallback path: full table fp32 [n][2] -> packed bf16 [n]
__global__ __launch_bounds__(256) void cvt_table(const F2* __restrict__ in,
                                                 unsigned* __restrict__ outb,
                                                 int n) {
  int i = blockIdx.x * 256 + threadIdx.x;
  if (i < n) {
    F2 v = in[i];
    outb[i] = bf2pack(v.x, v.y);
  }
}

// TBF=2 prep. Dense region [0,denseTotal): pair[j] = (bf16(T[j]),
// bf16(T[(j+1) mod level_size])) -- the x-neighbor pair, wrap folded in at
// build time so the runtime dense gather is ONE aligned 8B load with exact
// mod-size semantics. Hashed region [denseTotal,total): packed bf16 (4B).
__global__ __launch_bounds__(256) void prep_tables(
    const F2* __restrict__ in, unsigned long long* __restrict__ pair,
    unsigned* __restrict__ packed, EncParams P, unsigned denseTotal,
    unsigned total) {
  unsigned i = blockIdx.x * 256 + threadIdx.x;
  if (i >= total) return;
  F2 a = in[i];
  unsigned pa = bf2pack(a.x, a.y);
  if (i >= denseTotal) { packed[i] = pa; return; }
  unsigned off = 0, size = 0;
  #pragma unroll
  for (int l = 0; l < 12; ++l)
    if (i >= P.lv[l].offset) { off = P.lv[l].offset; size = P.lv[l].size; }
  unsigned j = i - off;
  unsigned j1 = (j + 1u == size) ? 0u : (j + 1u);
  F2 b = in[off + j1];
  pair[i] = ((unsigned long long)bf2pack(b.x, b.y) << 32) | (unsigned long long)pa;
}

// LDS map (bytes):
//   [0,5120)     sW0  bf16 [64 rows][32] row stride 80
//   [5120,7168)  sW1  bf16 [16 rows][64] stride 128, XOR-swizzled
//                (byte_col ^= (row&7)<<4); rows 8..15 zero
//   [7168,39936) per-wave region, 8192 B each: F bf16 [64][32] stride 80,
//                then overwritten by reluH bf16 [64][64] stride 128,
//                XOR-swizzled (byte_col ^= (row&7)<<4)
// 39936 B <= 40960 -> 4 blocks/CU (was 44544 -> 3 blocks/CU).
#define SMEM_BYTES 39936

// TBF=2: dense levels gather 8B pairs (2 loads/level), hashed levels gather
// packed bf16 (4B). TBF=1: packed bf16 everywhere (old path). TBF=0: fp32.
template <int TBF>
__global__ __launch_bounds__(256, 4) void plane_fwd(
    const F2* __restrict__ xy,
    const F2* __restrict__ table,
    const unsigned* __restrict__ tbf16,
    const unsigned long long* __restrict__ dpair,
    const float* __restrict__ w0g,
    const float* __restrict__ w1g,
    const int* __restrict__ boundp,
    float* __restrict__ out,
    EncParams P)
{
  __shared__ __align__(16) char smem[SMEM_BYTES];
  const int t = threadIdx.x;
  const int L = t & 63;
  const int w = t >> 6;
  const int r16 = L & 15;
  const int g = L >> 4;

  // ---- stage W0 (bf16, stride 80) ----
  {
    const float4* s = (const float4*)w0g;
    float4 a = s[t * 2], b = s[t * 2 + 1];
    uint4 pk = make_uint4(bf2pack(a.x, a.y), bf2pack(a.z, a.w),
                          bf2pack(b.x, b.y), bf2pack(b.z, b.w));
    *(uint4*)(smem + (t >> 2) * 80 + (t & 3) * 16) = pk;
  }
  // ---- stage W1 (bf16, [16][64] stride 128 swizzled, rows 8..15 = 0) ----
  {
    int row = t >> 4;
    int colb = (t & 15) * 8;  // byte column of 4 bf16
    float c0 = 0.f, c1 = 0.f, c2 = 0.f, c3 = 0.f;
    if (row < 8) {
      float4 wv = *(const float4*)(w1g + row * 64 + (t & 15) * 4);
      c0 = wv.x; c1 = wv.y; c2 = wv.z; c3 = wv.w;
    }
    *(uint2*)(smem + 5120 + row * 128 + (colb ^ ((row & 7) << 4))) =
        make_uint2(bf2pack(c0, c1), bf2pack(c2, c3));
  }

  char* sFH = smem + 7168 + w * 8192;

  // ---- hashgrid encode ----
  const int gid = blockIdx.x * 256 + t;
  const int p = gid >> 2;
  const int c = t & 3;
  F2 pxy = xy[p];

  int braw = boundp[0];
  float bf = (braw > 0x00800000) ? __int_as_float(braw) : (float)braw;
  float inv2b = 0.5f / bf;
  float xn = (pxy.x + bf) * inv2b;
  float yn = (pxy.y + bf) * inv2b;

  float cx  = fminf(fmaxf(xn * 2048.0f - 0.5f, 0.0f), 2047.0f);
  float cyv = fminf(fmaxf(yn * 2048.0f - 0.5f, 0.0f), 2047.0f);
  float cx0 = floorf(cx), cy0 = floorf(cyv);
  float u = cx - cx0, v = cyv - cy0;
  float cx1 = fminf(cx0 + 1.0f, 2047.0f);
  float cy1 = fminf(cy0 + 1.0f, 2047.0f);

  const float cxc = (c & 1) ? cx1 : cx0;
  const float cyc = (c & 2) ? cy1 : cy0;
  const float wc = ((c & 1) ? u : 1.0f - u) * ((c & 2) ? v : 1.0f - v);

  const float K = 1.0f / 2048.0f;
  const float gx = (cxc + 0.5f) * K;
  const float gy = (cyc + 0.5f) * K;

  unsigned fw[16];

  // Hashed levels (12..15) first: their gathers miss L2 (random lines) and
  // have the longest latency -- issue them earliest.
  #pragma unroll
  for (int lidx = 0; lidx < 16; ++lidx) {
    const int l = (lidx < 4) ? (12 + lidx) : (lidx - 4);
    const float scale   = P.lv[l].scale;
    const unsigned res  = P.lv[l].res;
    const unsigned size = P.lv[l].size;
    const unsigned off  = P.lv[l].offset;
    // TBF=2: compile-time split (host guarantees levels 12..15 hashed);
    // fallbacks keep the runtime wave-uniform test.
    const bool hashed = (TBF == 2) ? (l >= 12) : ((res * res) > size);

    float px = fmaf(gx, scale, 0.5f);
    float pgx = floorf(px);
    float frx = px - pgx;
    unsigned ux = (unsigned)pgx;

    float py = fmaf(gy, scale, 0.5f);
    float pgy = floorf(py);
    float fry = py - pgy;
    unsigned uy = (unsigned)pgy;

    F2 t00, t01, t10, t11;
    if (hashed) {
      const unsigned m = size - 1u;   // size == 2^19
      unsigned hy0 = uy * PRIME_Y;
      unsigned hy1 = hy0 + PRIME_Y;
      unsigned i00 = (ux ^ hy0) & m;
      unsigned i01 = (ux ^ hy1) & m;
      unsigned i10 = ((ux + 1u) ^ hy0) & m;
      unsigned i11 = ((ux + 1u) ^ hy1) & m;
      if (TBF >= 1) {
        const unsigned* tb = tbf16 + off;
        t00 = bf2unpack(tb[i00]);
        t01 = bf2unpack(tb[i01]);
        t10 = bf2unpack(tb[i10]);
        t11 = bf2unpack(tb[i11]);
      } else {
        const F2* tabp = table + off;
        t00 = tabp[i00]; t01 = tabp[i01]; t10 = tabp[i10]; t11 = tabp[i11];
      }
    } else {
      // v00 < size always (ux,uy <= res-1 -> v00 <= res^2-1 < size);
      // v01 needs at most one wrap.
      unsigned v00 = ux + uy * res;
      unsigned v01 = v00 + res;
      v01 = (v01 >= size) ? (v01 - size) : v01;
      if (TBF == 2) {
        const uint2* dp = (const uint2*)(dpair + off);
        uint2 d0 = dp[v00];   // (t00, t10) incl. build-time wrap
        uint2 d1 = dp[v01];   // (t01, t11)
        t00 = bf2unpack(d0.x); t10 = bf2unpack(d0.y);
        t01 = bf2unpack(d1.x); t11 = bf2unpack(d1.y);
      } else {
        unsigned v10 = v00 + 1u, v11 = v01 + 1u;
        unsigned i00 = v00;
        unsigned i01 = v01;
        unsigned i10 = (v10 >= size) ? (v10 - size) : v10;
        unsigned i11 = (v11 >= size) ? (v11 - size) : v11;
        if (TBF == 1) {
          const unsigned* tb = tbf16 + off;
          t00 = bf2unpack(tb[i00]);
          t01 = bf2unpack(tb[i01]);
          t10 = bf2unpack(tb[i10]);
          t11 = bf2unpack(tb[i11]);
        } else {
          const F2* tabp = table + off;
          t00 = tabp[i00]; t01 = tabp[i01]; t10 = tabp[i10]; t11 = tabp[i11];
        }
      }
    }

    float wx0 = 1.0f - frx, wx1 = frx;
    float wy0 = 1.0f - fry, wy1 = fry;
    float w00 = wx0 * wy0, w01 = wx0 * wy1, w10 = wx1 * wy0, w11 = wx1 * wy1;

    float fx = w00 * t00.x + w01 * t01.x + w10 * t10.x + w11 * t11.x;
    float fy = w00 * t00.y + w01 * t01.y + w10 * t10.y + w11 * t11.y;
    fw[l] = bf2pack(fx, fy);
  }

  *(uint4*)(sFH + L * 80 +  0) = make_uint4(fw[0],  fw[1],  fw[2],  fw[3]);
  *(uint4*)(sFH + L * 80 + 16) = make_uint4(fw[4],  fw[5],  fw[6],  fw[7]);
  *(uint4*)(sFH + L * 80 + 32) = make_uint4(fw[8],  fw[9],  fw[10], fw[11]);
  *(uint4*)(sFH + L * 80 + 48) = make_uint4(fw[12], fw[13], fw[14], fw[15]);

  __syncthreads();

  // ---- layer 1: Ht[j][m] = W0 . F^T ----
  short8 afr[4], bfr[4];
  #pragma unroll
  for (int b = 0; b < 4; ++b)
    bfr[b] = *(const short8*)(sFH + (16 * b + r16) * 80 + g * 16);
  #pragma unroll
  for (int a = 0; a < 4; ++a)
    afr[a] = *(const short8*)(smem + (16 * a + r16) * 80 + g * 16);

  f32x4 acc[4][4];
  #pragma unroll
  for (int a = 0; a < 4; ++a)
    #pragma unroll
    for (int b = 0; b < 4; ++b)
      acc[a][b] = (f32x4){0.f, 0.f, 0.f, 0.f};

  #pragma unroll
  for (int a = 0; a < 4; ++a)
    #pragma unroll
    for (int b = 0; b < 4; ++b)
      acc[a][b] = __builtin_amdgcn_mfma_f32_16x16x32_bf16(
          afr[a], bfr[b], acc[a][b], 0, 0, 0);

  // relu + bf16, write reluH[m][j] swizzled stride-128; j = 16a + 4g + reg
  #pragma unroll
  for (int a = 0; a < 4; ++a)
    #pragma unroll
    for (int b = 0; b < 4; ++b) {
      f32x4 h = acc[a][b];
      float h0 = fmaxf(h.x, 0.f), h1 = fmaxf(h.y, 0.f);
      float h2 = fmaxf(h.z, 0.f), h3 = fmaxf(h.w, 0.f);
      *(uint2*)(sFH + (16 * b + r16) * 128 +
                ((a * 32 + g * 8) ^ ((r16 & 7) << 4))) =
          make_uint2(bf2pack(h0, h1), bf2pack(h2, h3));
    }

  // No barrier here: reluH is wave-private; per-wave DS ordering (lgkmcnt)
  // is sufficient. (W0/W1 were covered by the barrier above.)

  // ---- layer 2: O^T[o][m] = W1 . reluH^T ----
  f32x4 oacc[4];
  #pragma unroll
  for (int b = 0; b < 4; ++b) oacc[b] = (f32x4){0.f, 0.f, 0.f, 0.f};

  #pragma unroll
  for (int ks = 0; ks < 2; ++ks) {
    short8 a2 = *(const short8*)(smem + 5120 + r16 * 128 +
                                 ((ks * 64 + g * 16) ^ ((r16 & 7) << 4)));
    #pragma unroll
    for (int b = 0; b < 4; ++b) {
      short8 b2 = *(const short8*)(sFH + (16 * b + r16) * 128 +
                                   ((ks * 64 + g * 16) ^ ((r16 & 7) << 4)));
      oacc[b] = __builtin_amdgcn_mfma_f32_16x16x32_bf16(a2, b2, oacc[b], 0, 0, 0);
    }
  }

  // ---- blend corners and store ----
  #pragma unroll
  for (int b = 0; b < 4; ++b) {
    float wcm = __shfl(wc, 16 * b + r16, 64);
    float v0 = oacc[b].x * wcm;
    float v1 = oacc[b].y * wcm;
    float v2 = oacc[b].z * wcm;
    float v3 = oacc[b].w * wcm;
    v0 += __shfl_xor(v0, 1, 64); v0 += __shfl_xor(v0, 2, 64);
    v1 += __shfl_xor(v1, 1, 64); v1 += __shfl_xor(v1, 2, 64);
    v2 += __shfl_xor(v2, 1, 64); v2 += __shfl_xor(v2, 2, 64);
    v3 += __shfl_xor(v3, 1, 64); v3 += __shfl_xor(v3, 2, 64);
    if ((L & 3) == 0 && g < 2) {
      int pt = blockIdx.x * 64 + w * 16 + 4 * b + (r16 >> 2);
      *(f32x4*)(out + (size_t)pt * 8 + 4 * g) = (f32x4){v0, v1, v2, v3};
    }
  }
}

extern "C" void kernel_launch(void* const* d_in, const int* in_sizes, int n_in,
                              void* d_out, int out_size, void* d_ws, size_t ws_size,
                              hipStream_t stream) {
  EncParams P;
  double b = exp2(log2(2048.0 / 16.0) / 15.0);
  unsigned off = 0;
  for (int l = 0; l < 16; ++l) {
    double s = 16.0 * pow(b, (double)l) - 1.0;
    int r = (int)ceil(s) + 1;
    unsigned p = (unsigned)(r * r);
    if (p > 524288u) p = 524288u;
    p = (p + 7u) / 8u * 8u;
    P.lv[l].scale = (float)s;
    P.lv[l].res = (unsigned)r;
    P.lv[l].size = p;
    P.lv[l].offset = off;
    off += p;
  }
  const int total_params = (int)off;

  // first hashed level (res^2 > size); expected 12 for this config
  int hstart = 16;
  for (int l = 0; l < 16; ++l) {
    unsigned long long rr = (unsigned long long)P.lv[l].res * P.lv[l].res;
    if (rr > P.lv[l].size) { hstart = l; break; }
  }
  const unsigned denseTotal = (hstart < 16) ? P.lv[hstart].offset
                                            : (unsigned)total_params;
  const size_t pairBytes = (size_t)denseTotal * 8;
  const size_t packBytes = (size_t)total_params * 4;

  const int N = in_sizes[0] / 2;  // xy is [N,2]
  const F2* xy = (const F2*)d_in[0];
  const F2* table = (const F2*)d_in[1];
  const float* w0g = (const float*)d_in[2];
  const float* w1g = (const float*)d_in[3];
  const int* bp = (const int*)d_in[4];
  float* outp = (float*)d_out;

  if (hstart == 12 && ws_size >= pairBytes + packBytes) {
    unsigned long long* pair = (unsigned long long*)d_ws;
    unsigned* tbf = (unsigned*)((char*)d_ws + pairBytes);
    prep_tables<<<(total_params + 255) / 256, 256, 0, stream>>>(
        table, pair, tbf, P, denseTotal, (unsigned)total_params);
    plane_fwd<2><<<N / 64, 256, 0, stream>>>(xy, table, tbf, pair, w0g, w1g,
                                             bp, outp, P);
  } else if (ws_size >= packBytes) {
    unsigned* tbf = (unsigned*)d_ws;
    cvt_table<<<(total_params + 255) / 256, 256, 0, stream>>>(table, tbf,
                                                              total_params);
    plane_fwd<1><<<N / 64, 256, 0, stream>>>(xy, table, tbf, nullptr, w0g, w1g,
                                             bp, outp, P);
  } else {
    plane_fwd<0><<<N / 64, 256, 0, stream>>>(xy, table, nullptr, nullptr, w0g,
                                             w1g, bp, outp, P);
  }
}

// Round 2
// 286.846 us; speedup vs baseline: 1.2348x; 1.0491x over previous
//
#include <hip/hip_runtime.h>
#include <math.h>

#define PRIME_Y 2654435761u

struct LevelParams { float scale; unsigned res; unsigned size; unsigned offset; };
struct EncParams { LevelParams lv[16]; };

typedef __attribute__((ext_vector_type(8))) short short8;
typedef __attribute__((ext_vector_type(4))) float f32x4;

struct alignas(8) F2 { float x, y; };

// fp32 pair -> packed bf16 (RNE), low = a, high = b.
__device__ inline unsigned bf2pack(float a, float b) {
  unsigned r;
  asm("v_cvt_pk_bf16_f32 %0, %1, %2" : "=v"(r) : "v"(a), "v"(b));
  return r;
}
__device__ inline F2 bf2unpack(unsigned u) {
  F2 r;
  r.x = __uint_as_float(u << 16);
  r.y = __uint_as_float(u & 0xFFFF0000u);
  return r;
}

// Fallback path: full table fp32 [n][2] -> packed bf16 [n]
__global__ __launch_bounds__(256) void cvt_table(const F2* __restrict__ in,
                                                 unsigned* __restrict__ outb,
                                                 int n) {
  int i = blockIdx.x * 256 + threadIdx.x;
  if (i < n) {
    F2 v = in[i];
    outb[i] = bf2pack(v.x, v.y);
  }
}

// TBF=2 prep. Dense region [0,denseTotal): pair[j] = (bf16(T[j]),
// bf16(T[(j+1) mod level_size])) -- x-neighbor pair, wrap folded in at build
// so the runtime dense gather is ONE aligned 8B load with exact mod-size
// semantics. Hashed region [denseTotal,total): packed bf16 (4B).
__global__ __launch_bounds__(256) void prep_tables(
    const F2* __restrict__ in, unsigned long long* __restrict__ pair,
    unsigned* __restrict__ packed, EncParams P, unsigned denseTotal,
    unsigned total) {
  unsigned i = blockIdx.x * 256 + threadIdx.x;
  if (i >= total) return;
  F2 a = in[i];
  unsigned pa = bf2pack(a.x, a.y);
  if (i >= denseTotal) { packed[i] = pa; return; }
  unsigned off = 0, size = 0;
  #pragma unroll
  for (int l = 0; l < 12; ++l)
    if (i >= P.lv[l].offset) { off = P.lv[l].offset; size = P.lv[l].size; }
  unsigned j = i - off;
  unsigned j1 = (j + 1u == size) ? 0u : (j + 1u);
  F2 b = in[off + j1];
  pair[i] = ((unsigned long long)bf2pack(b.x, b.y) << 32) | (unsigned long long)pa;
}

// LDS map (bytes):
//   [0,5120)     sW0  bf16 [64 rows][32] row stride 80
//   [5120,7168)  sW1  bf16 [16 rows][64] stride 128, XOR-swizzled
//                (byte_col ^= (row&7)<<4); rows 8..15 zero
//   [7168,39936) per-wave region, 8192 B each: F bf16 [64][32] stride 80,
//                then overwritten by reluH bf16 [64][64] stride 128 swizzled
// 39936 B <= 40960 -> 4 blocks/CU.
#define SMEM_BYTES 39936

// TBF=2: two-phase gather (all 40 loads in flight before first consume).
// R1 lesson: VGPR=52 meant the compiler serialized gathers in small groups;
// the kernel was latency-bound with no saturated pipe. Explicit address/issue
// phase + consume-in-issue-order gives incremental vmcnt drain.
template <int TBF>
__global__ __launch_bounds__(256, 4) void plane_fwd(
    const F2* __restrict__ xy,
    const F2* __restrict__ table,
    const unsigned* __restrict__ tbf16,
    const unsigned long long* __restrict__ dpair,
    const float* __restrict__ w0g,
    const float* __restrict__ w1g,
    const int* __restrict__ boundp,
    float* __restrict__ out,
    EncParams P)
{
  __shared__ __align__(16) char smem[SMEM_BYTES];
  const int t = threadIdx.x;
  const int L = t & 63;
  const int w = t >> 6;
  const int r16 = L & 15;
  const int g = L >> 4;

  // ---- stage W0 (bf16, stride 80) ----
  {
    const float4* s = (const float4*)w0g;
    float4 a = s[t * 2], b = s[t * 2 + 1];
    uint4 pk = make_uint4(bf2pack(a.x, a.y), bf2pack(a.z, a.w),
                          bf2pack(b.x, b.y), bf2pack(b.z, b.w));
    *(uint4*)(smem + (t >> 2) * 80 + (t & 3) * 16) = pk;
  }
  // ---- stage W1 (bf16, [16][64] stride 128 swizzled, rows 8..15 = 0) ----
  {
    int row = t >> 4;
    int colb = (t & 15) * 8;
    float c0 = 0.f, c1 = 0.f, c2 = 0.f, c3 = 0.f;
    if (row < 8) {
      float4 wv = *(const float4*)(w1g + row * 64 + (t & 15) * 4);
      c0 = wv.x; c1 = wv.y; c2 = wv.z; c3 = wv.w;
    }
    *(uint2*)(smem + 5120 + row * 128 + (colb ^ ((row & 7) << 4))) =
        make_uint2(bf2pack(c0, c1), bf2pack(c2, c3));
  }

  char* sFH = smem + 7168 + w * 8192;

  // ---- hashgrid encode ----
  const int gid = blockIdx.x * 256 + t;
  const int p = gid >> 2;
  const int c = t & 3;
  F2 pxy = xy[p];

  int braw = boundp[0];
  float bf = (braw > 0x00800000) ? __int_as_float(braw) : (float)braw;
  float inv2b = 0.5f / bf;
  float xn = (pxy.x + bf) * inv2b;
  float yn = (pxy.y + bf) * inv2b;

  float cx  = fminf(fmaxf(xn * 2048.0f - 0.5f, 0.0f), 2047.0f);
  float cyv = fminf(fmaxf(yn * 2048.0f - 0.5f, 0.0f), 2047.0f);
  float cx0 = floorf(cx), cy0 = floorf(cyv);
  float u = cx - cx0, v = cyv - cy0;
  float cx1 = fminf(cx0 + 1.0f, 2047.0f);
  float cy1 = fminf(cy0 + 1.0f, 2047.0f);

  const float cxc = (c & 1) ? cx1 : cx0;
  const float cyc = (c & 2) ? cy1 : cy0;
  const float wc = ((c & 1) ? u : 1.0f - u) * ((c & 2) ? v : 1.0f - v);

  const float K = 1.0f / 2048.0f;
  const float gx = (cxc + 0.5f) * K;
  const float gy = (cyc + 0.5f) * K;

  unsigned fw[16];

  if (TBF == 2) {
    // ============ phase 1: compute all addresses, issue all 40 loads ======
    // Hashed levels (12..15) first: random gathers = longest latency.
    unsigned hv[4][4];
    uint2 dv[12][2];

    #pragma unroll
    for (int li = 0; li < 4; ++li) {
      const int l = 12 + li;
      const float scale   = P.lv[l].scale;
      const unsigned size = P.lv[l].size;
      const unsigned off  = P.lv[l].offset;
      float px = fmaf(gx, scale, 0.5f);
      float py = fmaf(gy, scale, 0.5f);
      unsigned ux = (unsigned)floorf(px);
      unsigned uy = (unsigned)floorf(py);
      const unsigned m = size - 1u;   // size == 2^19
      unsigned hy0 = uy * PRIME_Y;
      unsigned hy1 = hy0 + PRIME_Y;
      const unsigned* tb = tbf16 + off;
      hv[li][0] = tb[(ux ^ hy0) & m];
      hv[li][1] = tb[(ux ^ hy1) & m];
      hv[li][2] = tb[((ux + 1u) ^ hy0) & m];
      hv[li][3] = tb[((ux + 1u) ^ hy1) & m];
    }
    #pragma unroll
    for (int l = 0; l < 12; ++l) {
      const float scale   = P.lv[l].scale;
      const unsigned res  = P.lv[l].res;
      const unsigned size = P.lv[l].size;
      const unsigned off  = P.lv[l].offset;
      float px = fmaf(gx, scale, 0.5f);
      float py = fmaf(gy, scale, 0.5f);
      unsigned ux = (unsigned)floorf(px);
      unsigned uy = (unsigned)floorf(py);
      unsigned v00 = ux + uy * res;      // < size always
      unsigned v01 = v00 + res;
      v01 = (v01 >= size) ? (v01 - size) : v01;
      const uint2* dp = (const uint2*)(dpair + off);
      dv[l][0] = dp[v00];   // (t00, t10) incl. build-time wrap
      dv[l][1] = dp[v01];   // (t01, t11)
    }

    // ============ phase 2: consume in issue order (incremental vmcnt) =====
    #pragma unroll
    for (int li = 0; li < 4; ++li) {
      const int l = 12 + li;
      const float scale = P.lv[l].scale;
      float px = fmaf(gx, scale, 0.5f);
      float py = fmaf(gy, scale, 0.5f);
      float frx = px - floorf(px);
      float fry = py - floorf(py);
      F2 t00 = bf2unpack(hv[li][0]);
      F2 t01 = bf2unpack(hv[li][1]);
      F2 t10 = bf2unpack(hv[li][2]);
      F2 t11 = bf2unpack(hv[li][3]);
      float wx0 = 1.0f - frx, wx1 = frx;
      float wy0 = 1.0f - fry, wy1 = fry;
      float w00 = wx0 * wy0, w01 = wx0 * wy1, w10 = wx1 * wy0, w11 = wx1 * wy1;
      float fx = w00 * t00.x + w01 * t01.x + w10 * t10.x + w11 * t11.x;
      float fy = w00 * t00.y + w01 * t01.y + w10 * t10.y + w11 * t11.y;
      fw[l] = bf2pack(fx, fy);
    }
    #pragma unroll
    for (int l = 0; l < 12; ++l) {
      const float scale = P.lv[l].scale;
      float px = fmaf(gx, scale, 0.5f);
      float py = fmaf(gy, scale, 0.5f);
      float frx = px - floorf(px);
      float fry = py - floorf(py);
      F2 t00 = bf2unpack(dv[l][0].x);
      F2 t10 = bf2unpack(dv[l][0].y);
      F2 t01 = bf2unpack(dv[l][1].x);
      F2 t11 = bf2unpack(dv[l][1].y);
      float wx0 = 1.0f - frx, wx1 = frx;
      float wy0 = 1.0f - fry, wy1 = fry;
      float w00 = wx0 * wy0, w01 = wx0 * wy1, w10 = wx1 * wy0, w11 = wx1 * wy1;
      float fx = w00 * t00.x + w01 * t01.x + w10 * t10.x + w11 * t11.x;
      float fy = w00 * t00.y + w01 * t01.y + w10 * t10.y + w11 * t11.y;
      fw[l] = bf2pack(fx, fy);
    }
  } else {
    // -------- fallback paths (TBF 0/1): original fused loop --------------
    #pragma unroll
    for (int lidx = 0; lidx < 16; ++lidx) {
      const int l = (lidx < 4) ? (12 + lidx) : (lidx - 4);
      const float scale   = P.lv[l].scale;
      const unsigned res  = P.lv[l].res;
      const unsigned size = P.lv[l].size;
      const unsigned off  = P.lv[l].offset;
      const bool hashed = (res * res) > size;

      float px = fmaf(gx, scale, 0.5f);
      float pgx = floorf(px);
      float frx = px - pgx;
      unsigned ux = (unsigned)pgx;

      float py = fmaf(gy, scale, 0.5f);
      float pgy = floorf(py);
      float fry = py - pgy;
      unsigned uy = (unsigned)pgy;

      unsigned i00, i01, i10, i11;
      if (hashed) {
        const unsigned m = size - 1u;
        unsigned hy0 = uy * PRIME_Y;
        unsigned hy1 = hy0 + PRIME_Y;
        i00 = (ux ^ hy0) & m;
        i01 = (ux ^ hy1) & m;
        i10 = ((ux + 1u) ^ hy0) & m;
        i11 = ((ux + 1u) ^ hy1) & m;
      } else {
        unsigned b0 = uy * res, b1 = b0 + res;
        unsigned q00 = ux + b0,      q01 = ux + b1;
        unsigned q10 = ux + 1u + b0, q11 = ux + 1u + b1;
        i00 = q00 >= size ? q00 - size : q00;
        i01 = q01 >= size ? q01 - size : q01;
        i10 = q10 >= size ? q10 - size : q10;
        i11 = q11 >= size ? q11 - size : q11;
      }

      F2 t00, t01, t10, t11;
      if (TBF == 1) {
        const unsigned* tb = tbf16 + off;
        t00 = bf2unpack(tb[i00]);
        t01 = bf2unpack(tb[i01]);
        t10 = bf2unpack(tb[i10]);
        t11 = bf2unpack(tb[i11]);
      } else {
        const F2* tabp = table + off;
        t00 = tabp[i00]; t01 = tabp[i01]; t10 = tabp[i10]; t11 = tabp[i11];
      }

      float wx0 = 1.0f - frx, wx1 = frx;
      float wy0 = 1.0f - fry, wy1 = fry;
      float w00 = wx0 * wy0, w01 = wx0 * wy1, w10 = wx1 * wy0, w11 = wx1 * wy1;
      float fx = w00 * t00.x + w01 * t01.x + w10 * t10.x + w11 * t11.x;
      float fy = w00 * t00.y + w01 * t01.y + w10 * t10.y + w11 * t11.y;
      fw[l] = bf2pack(fx, fy);
    }
  }

  *(uint4*)(sFH + L * 80 +  0) = make_uint4(fw[0],  fw[1],  fw[2],  fw[3]);
  *(uint4*)(sFH + L * 80 + 16) = make_uint4(fw[4],  fw[5],  fw[6],  fw[7]);
  *(uint4*)(sFH + L * 80 + 32) = make_uint4(fw[8],  fw[9],  fw[10], fw[11]);
  *(uint4*)(sFH + L * 80 + 48) = make_uint4(fw[12], fw[13], fw[14], fw[15]);

  __syncthreads();

  // ---- layer 1: Ht[j][m] = W0 . F^T ----
  short8 afr[4], bfr[4];
  #pragma unroll
  for (int b = 0; b < 4; ++b)
    bfr[b] = *(const short8*)(sFH + (16 * b + r16) * 80 + g * 16);
  #pragma unroll
  for (int a = 0; a < 4; ++a)
    afr[a] = *(const short8*)(smem + (16 * a + r16) * 80 + g * 16);

  f32x4 acc[4][4];
  #pragma unroll
  for (int a = 0; a < 4; ++a)
    #pragma unroll
    for (int b = 0; b < 4; ++b)
      acc[a][b] = (f32x4){0.f, 0.f, 0.f, 0.f};

  #pragma unroll
  for (int a = 0; a < 4; ++a)
    #pragma unroll
    for (int b = 0; b < 4; ++b)
      acc[a][b] = __builtin_amdgcn_mfma_f32_16x16x32_bf16(
          afr[a], bfr[b], acc[a][b], 0, 0, 0);

  // relu + bf16, write reluH[m][j] swizzled stride-128; j = 16a + 4g + reg
  #pragma unroll
  for (int a = 0; a < 4; ++a)
    #pragma unroll
    for (int b = 0; b < 4; ++b) {
      f32x4 h = acc[a][b];
      float h0 = fmaxf(h.x, 0.f), h1 = fmaxf(h.y, 0.f);
      float h2 = fmaxf(h.z, 0.f), h3 = fmaxf(h.w, 0.f);
      *(uint2*)(sFH + (16 * b + r16) * 128 +
                ((a * 32 + g * 8) ^ ((r16 & 7) << 4))) =
          make_uint2(bf2pack(h0, h1), bf2pack(h2, h3));
    }

  // No barrier: reluH is wave-private; per-wave DS ordering suffices.

  // ---- layer 2: O^T[o][m] = W1 . reluH^T ----
  f32x4 oacc[4];
  #pragma unroll
  for (int b = 0; b < 4; ++b) oacc[b] = (f32x4){0.f, 0.f, 0.f, 0.f};

  #pragma unroll
  for (int ks = 0; ks < 2; ++ks) {
    short8 a2 = *(const short8*)(smem + 5120 + r16 * 128 +
                                 ((ks * 64 + g * 16) ^ ((r16 & 7) << 4)));
    #pragma unroll
    for (int b = 0; b < 4; ++b) {
      short8 b2 = *(const short8*)(sFH + (16 * b + r16) * 128 +
                                   ((ks * 64 + g * 16) ^ ((r16 & 7) << 4)));
      oacc[b] = __builtin_amdgcn_mfma_f32_16x16x32_bf16(a2, b2, oacc[b], 0, 0, 0);
    }
  }

  // ---- blend corners and store ----
  #pragma unroll
  for (int b = 0; b < 4; ++b) {
    float wcm = __shfl(wc, 16 * b + r16, 64);
    float v0 = oacc[b].x * wcm;
    float v1 = oacc[b].y * wcm;
    float v2 = oacc[b].z * wcm;
    float v3 = oacc[b].w * wcm;
    v0 += __shfl_xor(v0, 1, 64); v0 += __shfl_xor(v0, 2, 64);
    v1 += __shfl_xor(v1, 1, 64); v1 += __shfl_xor(v1, 2, 64);
    v2 += __shfl_xor(v2, 1, 64); v2 += __shfl_xor(v2, 2, 64);
    v3 += __shfl_xor(v3, 1, 64); v3 += __shfl_xor(v3, 2, 64);
    if ((L & 3) == 0 && g < 2) {
      int pt = blockIdx.x * 64 + w * 16 + 4 * b + (r16 >> 2);
      *(f32x4*)(out + (size_t)pt * 8 + 4 * g) = (f32x4){v0, v1, v2, v3};
    }
  }
}

extern "C" void kernel_launch(void* const* d_in, const int* in_sizes, int n_in,
                              void* d_out, int out_size, void* d_ws, size_t ws_size,
                              hipStream_t stream) {
  EncParams P;
  double b = exp2(log2(2048.0 / 16.0) / 15.0);
  unsigned off = 0;
  for (int l = 0; l < 16; ++l) {
    double s = 16.0 * pow(b, (double)l) - 1.0;
    int r = (int)ceil(s) + 1;
    unsigned p = (unsigned)(r * r);
    if (p > 524288u) p = 524288u;
    p = (p + 7u) / 8u * 8u;
    P.lv[l].scale = (float)s;
    P.lv[l].res = (unsigned)r;
    P.lv[l].size = p;
    P.lv[l].offset = off;
    off += p;
  }
  const int total_params = (int)off;

  // first hashed level (res^2 > size); expected 12 for this config
  int hstart = 16;
  for (int l = 0; l < 16; ++l) {
    unsigned long long rr = (unsigned long long)P.lv[l].res * P.lv[l].res;
    if (rr > P.lv[l].size) { hstart = l; break; }
  }
  const unsigned denseTotal = (hstart < 16) ? P.lv[hstart].offset
                                            : (unsigned)total_params;
  const size_t pairBytes = (size_t)denseTotal * 8;
  const size_t packBytes = (size_t)total_params * 4;

  const int N = in_sizes[0] / 2;  // xy is [N,2]
  const F2* xy = (const F2*)d_in[0];
  const F2* table = (const F2*)d_in[1];
  const float* w0g = (const float*)d_in[2];
  const float* w1g = (const float*)d_in[3];
  const int* bp = (const int*)d_in[4];
  float* outp = (float*)d_out;

  if (hstart == 12 && ws_size >= pairBytes + packBytes) {
    unsigned long long* pair = (unsigned long long*)d_ws;
    unsigned* tbf = (unsigned*)((char*)d_ws + pairBytes);
    prep_tables<<<(total_params + 255) / 256, 256, 0, stream>>>(
        table, pair, tbf, P, denseTotal, (unsigned)total_params);
    plane_fwd<2><<<N / 64, 256, 0, stream>>>(xy, table, tbf, pair, w0g, w1g,
                                             bp, outp, P);
  } else if (ws_size >= packBytes) {
    unsigned* tbf = (unsigned*)d_ws;
    cvt_table<<<(total_params + 255) / 256, 256, 0, stream>>>(table, tbf,
                                                              total_params);
    plane_fwd<1><<<N / 64, 256, 0, stream>>>(xy, table, tbf, nullptr, w0g, w1g,
                                             bp, outp, P);
  } else {
    plane_fwd<0><<<N / 64, 256, 0, stream>>>(xy, table, nullptr, nullptr, w0g,
                                             w1g, bp, outp, P);
  }
}

// Round 4
// 248.358 us; speedup vs baseline: 1.4261x; 1.1550x over previous
//
#include <hip/hip_runtime.h>
#include <math.h>

#define PRIME_Y 2654435761u

struct LevelParams { float scale; unsigned res; unsigned size; unsigned offset; };
struct EncParams { LevelParams lv[16]; };

typedef __attribute__((ext_vector_type(8))) short short8;
typedef __attribute__((ext_vector_type(4))) float f32x4;

struct alignas(8) F2 { float x, y; };

// fp32 pair -> packed bf16 (RNE), low = a, high = b.
__device__ inline unsigned bf2pack(float a, float b) {
  unsigned r;
  asm("v_cvt_pk_bf16_f32 %0, %1, %2" : "=v"(r) : "v"(a), "v"(b));
  return r;
}
__device__ inline F2 bf2unpack(unsigned u) {
  F2 r;
  r.x = __uint_as_float(u << 16);
  r.y = __uint_as_float(u & 0xFFFF0000u);
  return r;
}

// Fallback: full table fp32 [n][2] -> packed bf16 [n]
__global__ __launch_bounds__(256) void cvt_table(const F2* __restrict__ in,
                                                 unsigned* __restrict__ outb,
                                                 int n) {
  int i = blockIdx.x * 256 + threadIdx.x;
  if (i < n) {
    F2 v = in[i];
    outb[i] = bf2pack(v.x, v.y);
  }
}

// TBF=3 prep. Dense [0,denseTotal): quad[v] = packed-bf16
// (T[v], T[(v+1)%sz], T[(v+res)%sz], T[(v+res+1)%sz]) -- one 16B load serves a
// full bilinear cell, wraps folded at build (exact reference semantics: the
// reference applies %size once to the final linear index).
// Hashed [denseTotal,total): packed bf16 (4B), stored at hp[i-denseTotal].
__global__ __launch_bounds__(256) void prep3(
    const F2* __restrict__ in, uint4* __restrict__ quad,
    unsigned* __restrict__ hp, EncParams P, unsigned denseTotal,
    unsigned total) {
  unsigned i = blockIdx.x * 256 + threadIdx.x;
  if (i >= total) return;
  if (i >= denseTotal) {
    F2 a = in[i];
    hp[i - denseTotal] = bf2pack(a.x, a.y);
    return;
  }
  unsigned off = 0, size = 0, res = 0;
  #pragma unroll
  for (int l = 0; l < 12; ++l)
    if (i >= P.lv[l].offset) {
      off = P.lv[l].offset; size = P.lv[l].size; res = P.lv[l].res;
    }
  unsigned j = i - off;
  unsigned j1 = j + 1u;        if (j1 >= size) j1 -= size;
  unsigned j2 = j + res;       if (j2 >= size) j2 -= size;
  unsigned j3 = j + res + 1u;  if (j3 >= size) j3 -= size;
  F2 a0 = in[off + j],  a1 = in[off + j1];
  F2 a2 = in[off + j2], a3 = in[off + j3];
  quad[i] = make_uint4(bf2pack(a0.x, a0.y), bf2pack(a1.x, a1.y),
                       bf2pack(a2.x, a2.y), bf2pack(a3.x, a3.y));
}

// LDS map (bytes):
//   [0,5120)     sW0  bf16 [64 rows][32] row stride 80
//   [5120,7168)  sW1  bf16 [16 rows][64] stride 128, XOR-swizzled
//   [7168,39936) per-wave region, 8192 B each: F bf16 [64][32] stride 80,
//                then overwritten by reluH bf16 [64][64] stride 128 swizzled
#define SMEM_BYTES 39936

// ============================================================================
// Primary kernel: 1 thread = 1 point (all 4 bilinear corners).
// R2 lesson: gather pipe is slot-throughput-bound (~1.3 slots/cyc/CU measured
// at both R0 and R2 operating points). 4 corner-threads issued 164 slots/point
// with ~2.7x redundancy; merged-thread + quad table + conditional union loads
// issue ~60 slots/point. Divergent `if(split)` loads cost no slots on masked
// lanes. MLP runs as 4 rounds (round r = corner r of the wave's 64 points),
// corner blend accumulated in registers via shfl of wc_r.
// ============================================================================
__global__ __launch_bounds__(256, 4) void plane_fwd1(
    const F2* __restrict__ xy,
    const uint4* __restrict__ qtab,     // dense quads, absolute entry index
    const unsigned* __restrict__ hp,    // hashed packed, base = denseTotal
    const float* __restrict__ w0g,
    const float* __restrict__ w1g,
    const int* __restrict__ boundp,
    float* __restrict__ out,
    EncParams P)
{
  __shared__ __align__(16) char smem[SMEM_BYTES];
  const int t = threadIdx.x;
  const int L = t & 63;
  const int w = t >> 6;
  const int r16 = L & 15;
  const int g = L >> 4;

  // ---- stage W0 (bf16, stride 80) ----
  {
    const float4* s = (const float4*)w0g;
    float4 a = s[t * 2], b = s[t * 2 + 1];
    uint4 pk = make_uint4(bf2pack(a.x, a.y), bf2pack(a.z, a.w),
                          bf2pack(b.x, b.y), bf2pack(b.z, b.w));
    *(uint4*)(smem + (t >> 2) * 80 + (t & 3) * 16) = pk;
  }
  // ---- stage W1 (bf16, [16][64] stride 128 swizzled, rows 8..15 = 0) ----
  {
    int row = t >> 4;
    int colb = (t & 15) * 8;
    float c0 = 0.f, c1 = 0.f, c2 = 0.f, c3 = 0.f;
    if (row < 8) {
      float4 wv = *(const float4*)(w1g + row * 64 + (t & 15) * 4);
      c0 = wv.x; c1 = wv.y; c2 = wv.z; c3 = wv.w;
    }
    *(uint2*)(smem + 5120 + row * 128 + (colb ^ ((row & 7) << 4))) =
        make_uint2(bf2pack(c0, c1), bf2pack(c2, c3));
  }

  char* sFH = smem + 7168 + w * 8192;

  // ---- per-point setup ----
  const int pt0 = blockIdx.x * 256 + t;
  F2 pxy = xy[pt0];

  int braw = boundp[0];
  float bf = (braw > 0x00800000) ? __int_as_float(braw) : (float)braw;
  float inv2b = 0.5f / bf;
  float xn = (pxy.x + bf) * inv2b;
  float yn = (pxy.y + bf) * inv2b;

  float cx  = fminf(fmaxf(xn * 2048.0f - 0.5f, 0.0f), 2047.0f);
  float cyv = fminf(fmaxf(yn * 2048.0f - 0.5f, 0.0f), 2047.0f);
  float cx0 = floorf(cx), cy0 = floorf(cyv);
  float u = cx - cx0, v = cyv - cy0;
  float cx1 = fminf(cx0 + 1.0f, 2047.0f);
  float cy1 = fminf(cy0 + 1.0f, 2047.0f);

  const float K = 1.0f / 2048.0f;
  const float gxc0 = (cx0 + 0.5f) * K, gxc1 = (cx1 + 0.5f) * K;
  const float gyc0 = (cy0 + 0.5f) * K, gyc1 = (cy1 + 0.5f) * K;

  unsigned fw[4][16];           // [corner][level], all indices static
  const unsigned denseOff = P.lv[12].offset;

  // ---- hashed levels 12..15 first (longest-latency random gathers) ----
  #pragma unroll
  for (int li = 0; li < 4; ++li) {
    const int l = 12 + li;
    const float scale   = P.lv[l].scale;
    const unsigned size = P.lv[l].size;
    const unsigned off  = P.lv[l].offset;
    const unsigned m = size - 1u;          // size == 2^19
    const unsigned* tb = hp + (off - denseOff);

    float px0 = fmaf(gxc0, scale, 0.5f), px1 = fmaf(gxc1, scale, 0.5f);
    float py0 = fmaf(gyc0, scale, 0.5f), py1 = fmaf(gyc1, scale, 0.5f);
    float fx0 = floorf(px0), fx1 = floorf(px1);
    float fy0 = floorf(py0), fy1 = floorf(py1);
    unsigned ux0 = (unsigned)fx0, ux1 = (unsigned)fx1;
    unsigned uy0 = (unsigned)fy0, uy1 = (unsigned)fy1;
    // delta <= 1.0 grid units -> ux1 in {ux0, ux0+1}
    bool xs = (ux1 != ux0), ys = (uy1 != uy0);

    unsigned hy0 = uy0 * PRIME_Y;
    unsigned hy1 = hy0 + PRIME_Y;
    unsigned hy2 = hy1 + PRIME_Y;

    // 3x3 union grid h[i][j] (i = x offset, j = y offset), outer ring
    // loaded only when the corresponding split occurs (exec-masked).
    unsigned h00 = tb[(ux0 ^ hy0) & m];
    unsigned h10 = tb[((ux0 + 1u) ^ hy0) & m];
    unsigned h01 = tb[(ux0 ^ hy1) & m];
    unsigned h11 = tb[((ux0 + 1u) ^ hy1) & m];
    unsigned h20 = 0u, h21 = 0u, h02 = 0u, h12 = 0u, h22 = 0u;
    if (xs)       { h20 = tb[((ux0 + 2u) ^ hy0) & m];
                    h21 = tb[((ux0 + 2u) ^ hy1) & m]; }
    if (ys)       { h02 = tb[(ux0 ^ hy2) & m];
                    h12 = tb[((ux0 + 1u) ^ hy2) & m]; }
    if (xs && ys) { h22 = tb[((ux0 + 2u) ^ hy2) & m]; }

    float frx0 = px0 - fx0, frx1 = px1 - fx1;
    float fry0 = py0 - fy0, fry1 = py1 - fy1;

    #pragma unroll
    for (int c = 0; c < 4; ++c) {
      const bool cH = (c & 1) != 0, cV = (c & 2) != 0;
      bool sx = cH && xs, sy = cV && ys;
      // entry(dx,dy) = h[dx + sx][dy + sy]
      unsigned e00 = sy ? (sx ? h11 : h01) : (sx ? h10 : h00);
      unsigned e10 = sy ? (sx ? h21 : h11) : (sx ? h20 : h10);
      unsigned e01 = sy ? (sx ? h12 : h02) : (sx ? h11 : h01);
      unsigned e11 = sy ? (sx ? h22 : h12) : (sx ? h21 : h11);
      float frx = cH ? frx1 : frx0;
      float fry = cV ? fry1 : fry0;
      F2 t00 = bf2unpack(e00), t10 = bf2unpack(e10);
      F2 t01 = bf2unpack(e01), t11 = bf2unpack(e11);
      float wx0 = 1.0f - frx, wx1 = frx;
      float wy0 = 1.0f - fry, wy1 = fry;
      float w00 = wx0 * wy0, w01 = wx0 * wy1, w10 = wx1 * wy0, w11 = wx1 * wy1;
      float fx = w00 * t00.x + w01 * t01.x + w10 * t10.x + w11 * t11.x;
      float fy = w00 * t00.y + w01 * t01.y + w10 * t10.y + w11 * t11.y;
      fw[c][l] = bf2pack(fx, fy);
    }
  }

  // ---- dense levels 0..11: quad loads (one 16B = full bilinear cell) ----
  #pragma unroll
  for (int l = 0; l < 12; ++l) {
    const float scale   = P.lv[l].scale;
    const unsigned res  = P.lv[l].res;
    const unsigned off  = P.lv[l].offset;
    const uint4* qt = qtab + off;

    float px0 = fmaf(gxc0, scale, 0.5f), px1 = fmaf(gxc1, scale, 0.5f);
    float py0 = fmaf(gyc0, scale, 0.5f), py1 = fmaf(gyc1, scale, 0.5f);
    float fx0 = floorf(px0), fx1 = floorf(px1);
    float fy0 = floorf(py0), fy1 = floorf(py1);
    unsigned ux0 = (unsigned)fx0, ux1 = (unsigned)fx1;
    unsigned uy0 = (unsigned)fy0, uy1 = (unsigned)fy1;
    bool xs = (ux1 != ux0), ys = (uy1 != uy0);

    // vA < size: ux,uy <= res-1 -> vA <= res^2-1 < size. Split variants
    // stay in-range for the same reason (ux0 <= res-2 when xs, etc).
    unsigned vA = ux0 + uy0 * res;
    uint4 qA = qt[vA];
    uint4 qB = make_uint4(0u, 0u, 0u, 0u);
    uint4 qC = make_uint4(0u, 0u, 0u, 0u);
    uint4 qD = make_uint4(0u, 0u, 0u, 0u);
    if (xs)       qB = qt[vA + 1u];
    if (ys)       qC = qt[vA + res];
    if (xs && ys) qD = qt[vA + res + 1u];

    float frx0 = px0 - fx0, frx1 = px1 - fx1;
    float fry0 = py0 - fy0, fry1 = py1 - fy1;

    #pragma unroll
    for (int c = 0; c < 4; ++c) {
      const bool cH = (c & 1) != 0, cV = (c & 2) != 0;
      bool sx = cH && xs, sy = cV && ys;
      unsigned qx = sy ? (sx ? qD.x : qC.x) : (sx ? qB.x : qA.x);
      unsigned qy = sy ? (sx ? qD.y : qC.y) : (sx ? qB.y : qA.y);
      unsigned qz = sy ? (sx ? qD.z : qC.z) : (sx ? qB.z : qA.z);
      unsigned qw = sy ? (sx ? qD.w : qC.w) : (sx ? qB.w : qA.w);
      float frx = cH ? frx1 : frx0;
      float fry = cV ? fry1 : fry0;
      F2 t00 = bf2unpack(qx), t10 = bf2unpack(qy);
      F2 t01 = bf2unpack(qz), t11 = bf2unpack(qw);
      float wx0 = 1.0f - frx, wx1 = frx;
      float wy0 = 1.0f - fry, wy1 = fry;
      float w00 = wx0 * wy0, w01 = wx0 * wy1, w10 = wx1 * wy0, w11 = wx1 * wy1;
      float fx = w00 * t00.x + w01 * t01.x + w10 * t10.x + w11 * t11.x;
      float fy = w00 * t00.y + w01 * t01.y + w10 * t10.y + w11 * t11.y;
      fw[c][l] = bf2pack(fx, fy);
    }
  }

  __syncthreads();   // W0/W1 staging visible to all waves

  f32x4 outacc[4];
  #pragma unroll
  for (int b = 0; b < 4; ++b) outacc[b] = (f32x4){0.f, 0.f, 0.f, 0.f};

  // ---- 4 MFMA rounds: round r = corner r of the wave's 64 points ----
  // All F/H traffic is wave-private; in-wave DS ordering (lgkmcnt) provides
  // write->read ordering without barriers (same reliance as R0..R2 kernels).
  #pragma unroll
  for (int r = 0; r < 4; ++r) {
    *(uint4*)(sFH + L * 80 +  0) =
        make_uint4(fw[r][0],  fw[r][1],  fw[r][2],  fw[r][3]);
    *(uint4*)(sFH + L * 80 + 16) =
        make_uint4(fw[r][4],  fw[r][5],  fw[r][6],  fw[r][7]);
    *(uint4*)(sFH + L * 80 + 32) =
        make_uint4(fw[r][8],  fw[r][9],  fw[r][10], fw[r][11]);
    *(uint4*)(sFH + L * 80 + 48) =
        make_uint4(fw[r][12], fw[r][13], fw[r][14], fw[r][15]);

    // F tiles into regs before H writes clobber the region
    short8 bfr[4];
    #pragma unroll
    for (int b = 0; b < 4; ++b)
      bfr[b] = *(const short8*)(sFH + (16 * b + r16) * 80 + g * 16);

    // layer 1, a-sliced (acc = 16 VGPRs instead of 64; keeps peak regs <128)
    #pragma unroll
    for (int a = 0; a < 4; ++a) {
      short8 afr = *(const short8*)(smem + (16 * a + r16) * 80 + g * 16);
      f32x4 acc[4];
      #pragma unroll
      for (int b = 0; b < 4; ++b) acc[b] = (f32x4){0.f, 0.f, 0.f, 0.f};
      #pragma unroll
      for (int b = 0; b < 4; ++b)
        acc[b] = __builtin_amdgcn_mfma_f32_16x16x32_bf16(afr, bfr[b], acc[b],
                                                         0, 0, 0);
      #pragma unroll
      for (int b = 0; b < 4; ++b) {
        f32x4 h = acc[b];
        float h0 = fmaxf(h.x, 0.f), h1 = fmaxf(h.y, 0.f);
        float h2 = fmaxf(h.z, 0.f), h3 = fmaxf(h.w, 0.f);
        *(uint2*)(sFH + (16 * b + r16) * 128 +
                  ((a * 32 + g * 8) ^ ((r16 & 7) << 4))) =
            make_uint2(bf2pack(h0, h1), bf2pack(h2, h3));
      }
    }

    // layer 2
    f32x4 oacc[4];
    #pragma unroll
    for (int b = 0; b < 4; ++b) oacc[b] = (f32x4){0.f, 0.f, 0.f, 0.f};
    #pragma unroll
    for (int ks = 0; ks < 2; ++ks) {
      short8 a2 = *(const short8*)(smem + 5120 + r16 * 128 +
                                   ((ks * 64 + g * 16) ^ ((r16 & 7) << 4)));
      #pragma unroll
      for (int b = 0; b < 4; ++b) {
        short8 b2 = *(const short8*)(sFH + (16 * b + r16) * 128 +
                                     ((ks * 64 + g * 16) ^ ((r16 & 7) << 4)));
        oacc[b] = __builtin_amdgcn_mfma_f32_16x16x32_bf16(a2, b2, oacc[b],
                                                          0, 0, 0);
      }
    }

    // corner blend: outacc += wc_r(point m) * O_r
    float wcr = ((r & 1) ? u : 1.0f - u) * ((r & 2) ? v : 1.0f - v);
    #pragma unroll
    for (int b = 0; b < 4; ++b) {
      float wcm = __shfl(wcr, 16 * b + r16, 64);
      outacc[b].x = fmaf(wcm, oacc[b].x, outacc[b].x);
      outacc[b].y = fmaf(wcm, oacc[b].y, outacc[b].y);
      outacc[b].z = fmaf(wcm, oacc[b].z, outacc[b].z);
      outacc[b].w = fmaf(wcm, oacc[b].w, outacc[b].w);
    }
  }

  // ---- store: lane (r16, g<2) holds point 16b+r16, outputs 4g..4g+3 ----
  if (g < 2) {
    #pragma unroll
    for (int b = 0; b < 4; ++b) {
      int pt = blockIdx.x * 256 + w * 64 + 16 * b + r16;
      *(f32x4*)(out + (size_t)pt * 8 + 4 * g) = outacc[b];
    }
  }
}

// ============================================================================
// Fallback kernel (old structure, 4 threads/point): TBF=1 packed / TBF=0 fp32
// ============================================================================
template <int TBF>
__global__ __launch_bounds__(256, 4) void plane_fwd(
    const F2* __restrict__ xy,
    const F2* __restrict__ table,
    const unsigned* __restrict__ tbf16,
    const float* __restrict__ w0g,
    const float* __restrict__ w1g,
    const int* __restrict__ boundp,
    float* __restrict__ out,
    EncParams P)
{
  __shared__ __align__(16) char smem[SMEM_BYTES];
  const int t = threadIdx.x;
  const int L = t & 63;
  const int w = t >> 6;
  const int r16 = L & 15;
  const int g = L >> 4;

  {
    const float4* s = (const float4*)w0g;
    float4 a = s[t * 2], b = s[t * 2 + 1];
    uint4 pk = make_uint4(bf2pack(a.x, a.y), bf2pack(a.z, a.w),
                          bf2pack(b.x, b.y), bf2pack(b.z, b.w));
    *(uint4*)(smem + (t >> 2) * 80 + (t & 3) * 16) = pk;
  }
  {
    int row = t >> 4;
    int colb = (t & 15) * 8;
    float c0 = 0.f, c1 = 0.f, c2 = 0.f, c3 = 0.f;
    if (row < 8) {
      float4 wv = *(const float4*)(w1g + row * 64 + (t & 15) * 4);
      c0 = wv.x; c1 = wv.y; c2 = wv.z; c3 = wv.w;
    }
    *(uint2*)(smem + 5120 + row * 128 + (colb ^ ((row & 7) << 4))) =
        make_uint2(bf2pack(c0, c1), bf2pack(c2, c3));
  }

  char* sFH = smem + 7168 + w * 8192;

  const int gid = blockIdx.x * 256 + t;
  const int p = gid >> 2;
  const int c = t & 3;
  F2 pxy = xy[p];

  int braw = boundp[0];
  float bf = (braw > 0x00800000) ? __int_as_float(braw) : (float)braw;
  float inv2b = 0.5f / bf;
  float xn = (pxy.x + bf) * inv2b;
  float yn = (pxy.y + bf) * inv2b;

  float cx  = fminf(fmaxf(xn * 2048.0f - 0.5f, 0.0f), 2047.0f);
  float cyv = fminf(fmaxf(yn * 2048.0f - 0.5f, 0.0f), 2047.0f);
  float cx0 = floorf(cx), cy0 = floorf(cyv);
  float u = cx - cx0, v = cyv - cy0;
  float cx1 = fminf(cx0 + 1.0f, 2047.0f);
  float cy1 = fminf(cy0 + 1.0f, 2047.0f);

  const float cxc = (c & 1) ? cx1 : cx0;
  const float cyc = (c & 2) ? cy1 : cy0;
  const float wc = ((c & 1) ? u : 1.0f - u) * ((c & 2) ? v : 1.0f - v);

  const float K = 1.0f / 2048.0f;
  const float gx = (cxc + 0.5f) * K;
  const float gy = (cyc + 0.5f) * K;

  unsigned fw[16];

  #pragma unroll
  for (int lidx = 0; lidx < 16; ++lidx) {
    const int l = (lidx < 4) ? (12 + lidx) : (lidx - 4);
    const float scale   = P.lv[l].scale;
    const unsigned res  = P.lv[l].res;
    const unsigned size = P.lv[l].size;
    const unsigned off  = P.lv[l].offset;
    const bool hashed = (res * res) > size;

    float px = fmaf(gx, scale, 0.5f);
    float pgx = floorf(px);
    float frx = px - pgx;
    unsigned ux = (unsigned)pgx;

    float py = fmaf(gy, scale, 0.5f);
    float pgy = floorf(py);
    float fry = py - pgy;
    unsigned uy = (unsigned)pgy;

    unsigned i00, i01, i10, i11;
    if (hashed) {
      const unsigned m = size - 1u;
      unsigned hy0 = uy * PRIME_Y;
      unsigned hy1 = hy0 + PRIME_Y;
      i00 = (ux ^ hy0) & m;
      i01 = (ux ^ hy1) & m;
      i10 = ((ux + 1u) ^ hy0) & m;
      i11 = ((ux + 1u) ^ hy1) & m;
    } else {
      unsigned b0 = uy * res, b1 = b0 + res;
      unsigned q00 = ux + b0,      q01 = ux + b1;
      unsigned q10 = ux + 1u + b0, q11 = ux + 1u + b1;
      i00 = q00 >= size ? q00 - size : q00;
      i01 = q01 >= size ? q01 - size : q01;
      i10 = q10 >= size ? q10 - size : q10;
      i11 = q11 >= size ? q11 - size : q11;
    }

    F2 t00, t01, t10, t11;
    if (TBF == 1) {
      const unsigned* tb = tbf16 + off;
      t00 = bf2unpack(tb[i00]);
      t01 = bf2unpack(tb[i01]);
      t10 = bf2unpack(tb[i10]);
      t11 = bf2unpack(tb[i11]);
    } else {
      const F2* tabp = table + off;
      t00 = tabp[i00]; t01 = tabp[i01]; t10 = tabp[i10]; t11 = tabp[i11];
    }

    float wx0 = 1.0f - frx, wx1 = frx;
    float wy0 = 1.0f - fry, wy1 = fry;
    float w00 = wx0 * wy0, w01 = wx0 * wy1, w10 = wx1 * wy0, w11 = wx1 * wy1;
    float fx = w00 * t00.x + w01 * t01.x + w10 * t10.x + w11 * t11.x;
    float fy = w00 * t00.y + w01 * t01.y + w10 * t10.y + w11 * t11.y;
    fw[l] = bf2pack(fx, fy);
  }

  *(uint4*)(sFH + L * 80 +  0) = make_uint4(fw[0],  fw[1],  fw[2],  fw[3]);
  *(uint4*)(sFH + L * 80 + 16) = make_uint4(fw[4],  fw[5],  fw[6],  fw[7]);
  *(uint4*)(sFH + L * 80 + 32) = make_uint4(fw[8],  fw[9],  fw[10], fw[11]);
  *(uint4*)(sFH + L * 80 + 48) = make_uint4(fw[12], fw[13], fw[14], fw[15]);

  __syncthreads();

  short8 afr[4], bfr[4];
  #pragma unroll
  for (int b = 0; b < 4; ++b)
    bfr[b] = *(const short8*)(sFH + (16 * b + r16) * 80 + g * 16);
  #pragma unroll
  for (int a = 0; a < 4; ++a)
    afr[a] = *(const short8*)(smem + (16 * a + r16) * 80 + g * 16);

  f32x4 acc[4][4];
  #pragma unroll
  for (int a = 0; a < 4; ++a)
    #pragma unroll
    for (int b = 0; b < 4; ++b)
      acc[a][b] = (f32x4){0.f, 0.f, 0.f, 0.f};

  #pragma unroll
  for (int a = 0; a < 4; ++a)
    #pragma unroll
    for (int b = 0; b < 4; ++b)
      acc[a][b] = __builtin_amdgcn_mfma_f32_16x16x32_bf16(
          afr[a], bfr[b], acc[a][b], 0, 0, 0);

  #pragma unroll
  for (int a = 0; a < 4; ++a)
    #pragma unroll
    for (int b = 0; b < 4; ++b) {
      f32x4 h = acc[a][b];
      float h0 = fmaxf(h.x, 0.f), h1 = fmaxf(h.y, 0.f);
      float h2 = fmaxf(h.z, 0.f), h3 = fmaxf(h.w, 0.f);
      *(uint2*)(sFH + (16 * b + r16) * 128 +
                ((a * 32 + g * 8) ^ ((r16 & 7) << 4))) =
          make_uint2(bf2pack(h0, h1), bf2pack(h2, h3));
    }

  f32x4 oacc[4];
  #pragma unroll
  for (int b = 0; b < 4; ++b) oacc[b] = (f32x4){0.f, 0.f, 0.f, 0.f};

  #pragma unroll
  for (int ks = 0; ks < 2; ++ks) {
    short8 a2 = *(const short8*)(smem + 5120 + r16 * 128 +
                                 ((ks * 64 + g * 16) ^ ((r16 & 7) << 4)));
    #pragma unroll
    for (int b = 0; b < 4; ++b) {
      short8 b2 = *(const short8*)(sFH + (16 * b + r16) * 128 +
                                   ((ks * 64 + g * 16) ^ ((r16 & 7) << 4)));
      oacc[b] = __builtin_amdgcn_mfma_f32_16x16x32_bf16(a2, b2, oacc[b], 0, 0, 0);
    }
  }

  #pragma unroll
  for (int b = 0; b < 4; ++b) {
    float wcm = __shfl(wc, 16 * b + r16, 64);
    float v0 = oacc[b].x * wcm;
    float v1 = oacc[b].y * wcm;
    float v2 = oacc[b].z * wcm;
    float v3 = oacc[b].w * wcm;
    v0 += __shfl_xor(v0, 1, 64); v0 += __shfl_xor(v0, 2, 64);
    v1 += __shfl_xor(v1, 1, 64); v1 += __shfl_xor(v1, 2, 64);
    v2 += __shfl_xor(v2, 1, 64); v2 += __shfl_xor(v2, 2, 64);
    v3 += __shfl_xor(v3, 1, 64); v3 += __shfl_xor(v3, 2, 64);
    if ((L & 3) == 0 && g < 2) {
      int pt = blockIdx.x * 64 + w * 16 + 4 * b + (r16 >> 2);
      *(f32x4*)(out + (size_t)pt * 8 + 4 * g) = (f32x4){v0, v1, v2, v3};
    }
  }
}

extern "C" void kernel_launch(void* const* d_in, const int* in_sizes, int n_in,
                              void* d_out, int out_size, void* d_ws, size_t ws_size,
                              hipStream_t stream) {
  EncParams P;
  double b = exp2(log2(2048.0 / 16.0) / 15.0);
  unsigned off = 0;
  for (int l = 0; l < 16; ++l) {
    double s = 16.0 * pow(b, (double)l) - 1.0;
    int r = (int)ceil(s) + 1;
    unsigned p = (unsigned)(r * r);
    if (p > 524288u) p = 524288u;
    p = (p + 7u) / 8u * 8u;
    P.lv[l].scale = (float)s;
    P.lv[l].res = (unsigned)r;
    P.lv[l].size = p;
    P.lv[l].offset = off;
    off += p;
  }
  const int total_params = (int)off;

  int hstart = 16;
  for (int l = 0; l < 16; ++l) {
    unsigned long long rr = (unsigned long long)P.lv[l].res * P.lv[l].res;
    if (rr > P.lv[l].size) { hstart = l; break; }
  }
  const unsigned denseTotal = (hstart < 16) ? P.lv[hstart].offset
                                            : (unsigned)total_params;
  const size_t quadBytes = (size_t)denseTotal * 16;
  const size_t hashBytes = (size_t)((unsigned)total_params - denseTotal) * 4;
  const size_t packBytes = (size_t)total_params * 4;

  const int N = in_sizes[0] / 2;  // xy is [N,2]
  const F2* xy = (const F2*)d_in[0];
  const F2* table = (const F2*)d_in[1];
  const float* w0g = (const float*)d_in[2];
  const float* w1g = (const float*)d_in[3];
  const int* bp = (const int*)d_in[4];
  float* outp = (float*)d_out;

  if (hstart == 12 && (N & 255) == 0 && ws_size >= quadBytes + hashBytes) {
    uint4* quad = (uint4*)d_ws;
    unsigned* hp = (unsigned*)((char*)d_ws + quadBytes);
    prep3<<<(total_params + 255) / 256, 256, 0, stream>>>(
        table, quad, hp, P, denseTotal, (unsigned)total_params);
    plane_fwd1<<<N / 256, 256, 0, stream>>>(xy, quad, hp, w0g, w1g, bp,
                                            outp, P);
  } else if (ws_size >= packBytes) {
    unsigned* tbf = (unsigned*)d_ws;
    cvt_table<<<(total_params + 255) / 256, 256, 0, stream>>>(table, tbf,
                                                              total_params);
    plane_fwd<1><<<N / 64, 256, 0, stream>>>(xy, table, tbf, w0g, w1g, bp,
                                             outp, P);
  } else {
    plane_fwd<0><<<N / 64, 256, 0, stream>>>(xy, table, nullptr, w0g, w1g, bp,
                                             outp, P);
  }
}